// Round 6
// baseline (137.888 us; speedup 1.0000x reference)
//
#include <hip/hip_runtime.h>
#include <cstdint>
#include <math.h>

// B=128 rows, V=128000 vocab. fp32 logits/noise/temps -> int32 argmax index.
#define BB 128
#define VV 128000
#define SPLITS 25                // 128000/25 = 5120 = 256 threads * 20 elems EXACT
#define CHUNK (VV / SPLITS)      // 5120 floats per block
#define TPB 256
#define STRIDE (TPB * 4)         // 1024 floats between unroll steps
#define ITERS 5                  // 5 float4 per thread
#define WCHUNK (CHUNK / 4)       // 1280 floats staged per wave per stream

// native clang vector type — NT/aligned vector ops
typedef float vfloat4 __attribute__((ext_vector_type(4)));

// Map fp32 to order-preserving uint32 (no NaNs in this problem).
__device__ __forceinline__ uint32_t sortable(float f) {
    uint32_t u = __float_as_uint(f);
    return (u & 0x80000000u) ? ~u : (u | 0x80000000u);
}

__device__ __forceinline__ uint64_t kmax(uint64_t a, uint64_t b) {
    return a > b ? a : b;
}

__device__ __forceinline__ vfloat4 nt_load4(const float* p) {
    return __builtin_nontemporal_load(reinterpret_cast<const vfloat4*>(p));
}

// async global->LDS DMA, 16 B per lane. LDS dest = wave-uniform base + lane*16,
// so gptr must be g_base + lane*16 with g_base wave-uniform. Counter: vmcnt.
__device__ __forceinline__ void load_lds16(const float* g, float* s) {
    __builtin_amdgcn_global_load_lds(
        (const __attribute__((address_space(1))) void*)g,
        (__attribute__((address_space(3))) void*)s,
        16, 0, 0);
}

__global__ __launch_bounds__(TPB) void sampler_partial(
    const float* __restrict__ logits,
    const float* __restrict__ temps,
    const float* __restrict__ noise,
    uint64_t* __restrict__ pkey)
{
    __shared__ __align__(16) float s_l[CHUNK];   // 20 KB
    __shared__ __align__(16) float s_e[CHUNK];   // 20 KB
    __shared__ uint64_t sk[TPB / 64];

    const int blk = blockIdx.x;
    const int row = blk / SPLITS;
    const int seg = blk - row * SPLITS;

    const float t = temps[row];
    const bool greedy = (t == 0.0f);          // block-uniform branch
    const float invt = greedy ? 1.0f : (1.0f / t);

    const float* lrow = logits + (size_t)row * VV + (size_t)(seg * CHUNK);
    const float* erow = noise  + (size_t)row * VV + (size_t)(seg * CHUNK);

    const int lane = threadIdx.x & 63;
    const int wave = threadIdx.x >> 6;
    const int i0   = seg * CHUNK + (int)threadIdx.x * 4;

    float bv = -INFINITY;
    int   bi = 0;

    if (greedy) {
        // greedy rows: logits only, direct NT vector loads (no noise bytes)
        const float* lp = lrow + threadIdx.x * 4;
        vfloat4 l[ITERS];
        #pragma unroll
        for (int j = 0; j < ITERS; ++j) l[j] = nt_load4(lp + j * STRIDE);
        #pragma unroll
        for (int j = 0; j < ITERS; ++j) {
            #pragma unroll
            for (int c = 0; c < 4; ++c) {
                const float v = l[j][c];
                // ascending index + strict '>' keeps FIRST occurrence
                if (v > bv) { bv = v; bi = i0 + j * STRIDE + c; }
            }
        }
        __syncthreads();   // keep barrier count uniform with the other path
    } else {
        // sampled rows: stage BOTH streams via LDS-direct DMA (bypass VGPR
        // return path). Wave w stages floats [w*1280, (w+1)*1280) of each
        // stream: 5 calls x 1 KB per stream, 10 KB in flight per wave.
        const int wbase = wave * WCHUNK;
        #pragma unroll
        for (int j = 0; j < 5; ++j)
            load_lds16(lrow + wbase + j * 256 + lane * 4, &s_l[wbase + j * 256]);
        #pragma unroll
        for (int j = 0; j < 5; ++j)
            load_lds16(erow + wbase + j * 256 + lane * 4, &s_e[wbase + j * 256]);
        __syncthreads();   // drains vmcnt(0) then barrier

        const int tb = (int)threadIdx.x * 4;
        #pragma unroll
        for (int j = 0; j < ITERS; ++j) {
            const vfloat4 l = *reinterpret_cast<const vfloat4*>(&s_l[tb + j * STRIDE]);
            const vfloat4 e = *reinterpret_cast<const vfloat4*>(&s_e[tb + j * STRIDE]);
            #pragma unroll
            for (int c = 0; c < 4; ++c) {
                const float s = l[c] * invt - logf(fmaxf(e[c], 1e-10f));
                if (s > bv) { bv = s; bi = i0 + j * STRIDE + c; }
            }
        }
    }

    // Pack (value, ~index): u64 max == argmax with smallest-index tie-break.
    uint64_t key = ((uint64_t)sortable(bv) << 32) | (uint32_t)(~(uint32_t)bi);

    // wave64 shuffle reduction
    #pragma unroll
    for (int off = 32; off > 0; off >>= 1) {
        uint64_t ok = __shfl_down(key, off, 64);
        key = kmax(key, ok);
    }

    if (lane == 0) sk[wave] = key;
    __syncthreads();
    if (threadIdx.x == 0) {
        #pragma unroll
        for (int w = 1; w < TPB / 64; ++w) key = kmax(key, sk[w]);
        pkey[blk] = key;
    }
}

__global__ __launch_bounds__(BB) void sampler_reduce(
    const uint64_t* __restrict__ pkey,
    int* __restrict__ out)
{
    const int r = threadIdx.x;                 // 128 threads, 1 block
    uint64_t key = pkey[r * SPLITS];
    #pragma unroll
    for (int s = 1; s < SPLITS; ++s)
        key = kmax(key, pkey[r * SPLITS + s]);
    out[r] = (int)(~(uint32_t)(key & 0xffffffffu));
}

extern "C" void kernel_launch(void* const* d_in, const int* in_sizes, int n_in,
                              void* d_out, int out_size, void* d_ws, size_t ws_size,
                              hipStream_t stream) {
    const float* logits = (const float*)d_in[0];   // [B, V] fp32
    const float* temps  = (const float*)d_in[1];   // [B]    fp32
    const float* noise  = (const float*)d_in[2];   // [B, V] fp32
    int* out = (int*)d_out;                        // [B]    int32

    uint64_t* pkey = (uint64_t*)d_ws;              // BB*SPLITS u64 = 25.6 KB

    sampler_partial<<<BB * SPLITS, TPB, 0, stream>>>(logits, temps, noise, pkey);
    sampler_reduce<<<1, BB, 0, stream>>>(pkey, out);
}